// Round 4
// baseline (524.442 us; speedup 1.0000x reference)
//
#include <hip/hip_runtime.h>

// 2-layer LSTM (HID=10), B=2048, T=1024 main + F=64 future steps.
// Round 4: one element per wave (2048 waves = 2/SIMD on all 1024 SIMDs).
// Lane L = k*10+u owns gate row L. KEY CHANGE vs round 3: h1/h2 are
// wave-uniform -> broadcast via v_readlane into SGPRs (not ds_bpermute into
// per-lane VGPR arrays). hh-dots become v_fma(sgpr_h, vgpr_w, acc); the
// 20-float h arrays that forced AGPR shuttling (VGPR_Count=36 + accvgpr
// traffic in round 3) are gone. Cell update on lanes 0..9 only (i-act local,
// f/g/o via 3 bperm). 6 DS ops/step instead of 28.

#define NB 2048
#define TMAIN 1024
#define HID 10

#define PIN(v) asm volatile("" : "+v"(v))

__global__ __launch_bounds__(64, 2) void lstm2_kernel(
    const float* __restrict__ x,
    const float* __restrict__ Wih1, const float* __restrict__ Whh1,
    const float* __restrict__ bih1, const float* __restrict__ bhh1,
    const float* __restrict__ Wih2, const float* __restrict__ Whh2,
    const float* __restrict__ bih2, const float* __restrict__ bhh2,
    const float* __restrict__ Wlin, const float* __restrict__ blin,
    const int* __restrict__ futp,
    float* __restrict__ out)
{
    const int lane = threadIdx.x;
    const int ge   = blockIdx.x;          // one batch element per block
    const int F    = futp[0];
    const int OUTW = TMAIN + F;

    const int L = (lane < 40) ? lane : 0; // lanes 40..63 shadow lane 0
    const int k = L / HID;                // gate: 0=i 1=f 2=g 3=o
    const int u = L - k * HID;            // hidden unit

    // ---- per-lane weights (row L) ----
    float whh1v[HID], wih2v[HID], whh2v[HID], wlinv[HID];
    #pragma unroll
    for (int j = 0; j < HID; ++j) {
        whh1v[j] = Whh1[L * HID + j];
        wih2v[j] = Wih2[L * HID + j];
        whh2v[j] = Whh2[L * HID + j];
        wlinv[j] = Wlin[j];               // uniform but kept in VGPR (sgpr slot
    }                                     // is used by h2 in the head fmas)
    float wih1v = Wih1[L];
    float b1 = bih1[L] + bhh1[L];
    float b2 = bih2[L] + bhh2[L];
    float bl = blin[0];

    #pragma unroll
    for (int j = 0; j < HID; ++j) { PIN(whh1v[j]); PIN(wih2v[j]); PIN(whh2v[j]); PIN(wlinv[j]); }
    PIN(wih1v); PIN(b1); PIN(b2); PIN(bl);

    // activation constants: tanh for g-gate lanes, sigmoid otherwise
    const bool isg = (k == 2);
    const float aK = isg ?  2.8853900817779268f : -1.4426950408889634f;
    const float aA = isg ?  1.0f : 0.0f;
    const float aB = isg ? -2.0f : 1.0f;
    const float tK = 2.8853900817779268f, tA = 1.0f, tB = -2.0f;

    // act-gather bperm addresses (meaningful on lanes 0..9; executed wave-wide)
    const int adr_f = (1 * HID + u) * 4;
    const int adr_g = (2 * HID + u) * 4;
    const int adr_o = (3 * HID + u) * 4;

    auto bp = [](int addr, float v) -> float {
        return __int_as_float(__builtin_amdgcn_ds_bpermute(addr, __float_as_int(v)));
    };
    auto rl = [](float v, int j) -> float {
        return __int_as_float(__builtin_amdgcn_readlane(__float_as_int(v), j));
    };

    // ---- state: c on lanes 0..9; h wave-uniform in SGPR-held arrays ----
    float c1 = 0.f, c2 = 0.f;
    float h1s[HID], h2s[HID];
    #pragma unroll
    for (int j = 0; j < HID; ++j) { h1s[j] = 0.f; h2s[j] = 0.f; }

    auto step = [&](float xt) -> float {
        // ---- cell 1: gate pre-acts (2 accumulator chains for ILP) ----
        float a0 = fmaf(xt, wih1v, b1);
        float a1 = h1s[5] * whh1v[5];
        #pragma unroll
        for (int j = 0; j < 5; ++j) {
            a0 = fmaf(h1s[j], whh1v[j], a0);
            if (j) a1 = fmaf(h1s[5 + j], whh1v[5 + j], a1);
        }
        float a = a0 + a1;
        float act = fmaf(aB, __builtin_amdgcn_rcpf(1.0f + __builtin_amdgcn_exp2f(aK * a)), aA);
        // lanes 0..9: i-act is local; gather f/g/o
        float gf = bp(adr_f, act);
        float gg = bp(adr_g, act);
        float go = bp(adr_o, act);
        c1 = fmaf(gf, c1, act * gg);
        float tc = fmaf(tB, __builtin_amdgcn_rcpf(1.0f + __builtin_amdgcn_exp2f(tK * c1)), tA);
        float h1u = go * tc;
        #pragma unroll
        for (int j = 0; j < HID; ++j) h1s[j] = rl(h1u, j);

        // ---- cell 2 ----
        float d0 = b2;
        float d1 = h2s[0] * whh2v[0];
        #pragma unroll
        for (int j = 0; j < HID; ++j) {
            d0 = fmaf(h1s[j], wih2v[j], d0);
            if (j) d1 = fmaf(h2s[j], whh2v[j], d1);
        }
        float d = d0 + d1;
        float act2 = fmaf(aB, __builtin_amdgcn_rcpf(1.0f + __builtin_amdgcn_exp2f(aK * d)), aA);
        float qf = bp(adr_f, act2);
        float qg = bp(adr_g, act2);
        float qo = bp(adr_o, act2);
        c2 = fmaf(qf, c2, act2 * qg);
        float tc2 = fmaf(tB, __builtin_amdgcn_rcpf(1.0f + __builtin_amdgcn_exp2f(tK * c2)), tA);
        float h2u = qo * tc2;
        #pragma unroll
        for (int j = 0; j < HID; ++j) h2s[j] = rl(h2u, j);

        // ---- linear head: sgpr h2 x vgpr wlin ----
        float y = bl;
        #pragma unroll
        for (int j = 0; j < HID; ++j) y = fmaf(h2s[j], wlinv[j], y);
        return y;
    };

    // ---- main loop: 4 steps/group, x prefetched one group ahead ----
    const float4* xrow = (const float4*)(x + (size_t)ge * TMAIN);  // wave-uniform -> s_load
    float4* orow = (float4*)(out + (size_t)ge * OUTW);             // OUTW=1088, rows 16B-aligned
    float4 xv = xrow[0];
    float yprev = 0.f;
    #pragma unroll 1
    for (int t4 = 0; t4 < TMAIN / 4; ++t4) {
        float4 xn = (t4 + 1 < TMAIN / 4) ? xrow[t4 + 1] : make_float4(0.f, 0.f, 0.f, 0.f);
        float4 yv;
        yv.x = step(xv.x);
        yv.y = step(xv.y);
        yv.z = step(xv.z);
        yv.w = step(xv.w);
        if (lane == 0) orow[t4] = yv;
        yprev = yv.w;
        xv = xn;
    }

    // ---- future loop: y feeds back (uniform on all lanes) ----
    int t = 0;
    #pragma unroll 1
    for (; t + 3 < F; t += 4) {
        float4 yv;
        yv.x = step(yprev);
        yv.y = step(yv.x);
        yv.z = step(yv.y);
        yv.w = step(yv.z);
        if (lane == 0) orow[(TMAIN + t) / 4] = yv;
        yprev = yv.w;
    }
    #pragma unroll 1
    for (; t < F; ++t) {
        yprev = step(yprev);
        if (lane == 0) out[(size_t)ge * OUTW + TMAIN + t] = yprev;
    }
}

extern "C" void kernel_launch(void* const* d_in, const int* in_sizes, int n_in,
                              void* d_out, int out_size, void* d_ws, size_t ws_size,
                              hipStream_t stream) {
    const float* x    = (const float*)d_in[0];
    const float* Wih1 = (const float*)d_in[1];
    const float* Whh1 = (const float*)d_in[2];
    const float* bih1 = (const float*)d_in[3];
    const float* bhh1 = (const float*)d_in[4];
    const float* Wih2 = (const float*)d_in[5];
    const float* Whh2 = (const float*)d_in[6];
    const float* bih2 = (const float*)d_in[7];
    const float* bhh2 = (const float*)d_in[8];
    const float* Wlin = (const float*)d_in[9];
    const float* blin = (const float*)d_in[10];
    const int*   futp = (const int*)d_in[11];
    float* out = (float*)d_out;

    lstm2_kernel<<<NB, 64, 0, stream>>>(x, Wih1, Whh1, bih1, bhh1,
                                        Wih2, Whh2, bih2, bhh2,
                                        Wlin, blin, futp, out);
}

// Round 5
// 509.943 us; speedup vs baseline: 1.0284x; 1.0284x over previous
//
#include <hip/hip_runtime.h>

// 2-layer LSTM (HID=10), B=2048, T=1024 main + F=64 future steps.
// One element per wave, 2048 single-wave blocks = 2 waves/SIMD on all 1024 SIMDs.
// Lane L = k*10+u owns gate row L; h1/h2 wave-uniform in SGPRs via v_readlane;
// c-update on lanes 0..9 (f/g/o acts gathered by 3 ds_bpermute).
//
// Round 5 fix: __launch_bounds__' 2nd arg is only a MIN waves/EU -- the
// allocator was still chasing 8 waves/EU, squeezing arch VGPRs to 40 and
// shuttling the ~44 loop-invariant weights through AGPRs (v_accvgpr_read per
// use ~= +100 VALU inst/step; rounds 3-4 both ~485us). amdgpu_waves_per_eu(2,2)
// pins the budget at 256 VGPRs (occupancy is block-limited at 2 waves/SIMD
// anyway), so weights stay in arch VGPRs. Also: activation scale aK folded
// into gate weights/biases at load time.

#define NB 2048
#define TMAIN 1024
#define HID 10

#define PIN(v) asm volatile("" : "+v"(v))

__global__ __launch_bounds__(64)
__attribute__((amdgpu_waves_per_eu(2, 2)))
void lstm2_kernel(
    const float* __restrict__ x,
    const float* __restrict__ Wih1, const float* __restrict__ Whh1,
    const float* __restrict__ bih1, const float* __restrict__ bhh1,
    const float* __restrict__ Wih2, const float* __restrict__ Whh2,
    const float* __restrict__ bih2, const float* __restrict__ bhh2,
    const float* __restrict__ Wlin, const float* __restrict__ blin,
    const int* __restrict__ futp,
    float* __restrict__ out)
{
    const int lane = threadIdx.x;
    const int ge   = blockIdx.x;          // one batch element per block
    const int F    = futp[0];
    const int OUTW = TMAIN + F;

    const int L = (lane < 40) ? lane : 0; // lanes 40..63 shadow lane 0
    const int k = L / HID;                // gate: 0=i 1=f 2=g 3=o
    const int u = L - k * HID;            // hidden unit

    // activation: sigma/tanh both = A + B*rcp(1 + exp2(K*x)); K folded into W,b
    const bool isg = (k == 2);
    const float aK = isg ?  2.8853900817779268f : -1.4426950408889634f;
    const float aA = isg ?  1.0f : 0.0f;
    const float aB = isg ? -2.0f : 1.0f;
    const float tK = 2.8853900817779268f, tA = 1.0f, tB = -2.0f;

    // ---- per-lane weights (row L), pre-scaled by aK ----
    float whh1v[HID], wih2v[HID], whh2v[HID], wlinv[HID];
    #pragma unroll
    for (int j = 0; j < HID; ++j) {
        whh1v[j] = Whh1[L * HID + j] * aK;
        wih2v[j] = Wih2[L * HID + j] * aK;
        whh2v[j] = Whh2[L * HID + j] * aK;
        wlinv[j] = Wlin[j];
    }
    float wih1v = Wih1[L] * aK;
    float b1 = (bih1[L] + bhh1[L]) * aK;
    float b2 = (bih2[L] + bhh2[L]) * aK;
    float bl = blin[0];

    #pragma unroll
    for (int j = 0; j < HID; ++j) { PIN(whh1v[j]); PIN(wih2v[j]); PIN(whh2v[j]); PIN(wlinv[j]); }
    PIN(wih1v); PIN(b1); PIN(b2); PIN(bl);

    // act-gather bperm addresses (meaningful on lanes 0..9; executed wave-wide)
    const int adr_f = (1 * HID + u) * 4;
    const int adr_g = (2 * HID + u) * 4;
    const int adr_o = (3 * HID + u) * 4;

    auto bp = [](int addr, float v) -> float {
        return __int_as_float(__builtin_amdgcn_ds_bpermute(addr, __float_as_int(v)));
    };
    auto rl = [](float v, int j) -> float {
        return __int_as_float(__builtin_amdgcn_readlane(__float_as_int(v), j));
    };

    // ---- state: c on lanes 0..9; h wave-uniform (SGPRs) ----
    float c1 = 0.f, c2 = 0.f;
    float h1s[HID], h2s[HID];
    #pragma unroll
    for (int j = 0; j < HID; ++j) { h1s[j] = 0.f; h2s[j] = 0.f; }

    auto step = [&](float xt) -> float {
        // ---- cell 1: gate pre-act (pre-scaled), 2 chains for ILP ----
        float a0 = fmaf(xt, wih1v, b1);
        float a1 = h1s[5] * whh1v[5];
        #pragma unroll
        for (int j = 0; j < 5; ++j) {
            a0 = fmaf(h1s[j], whh1v[j], a0);
            if (j) a1 = fmaf(h1s[5 + j], whh1v[5 + j], a1);
        }
        float a = a0 + a1;
        float act = fmaf(aB, __builtin_amdgcn_rcpf(1.0f + __builtin_amdgcn_exp2f(a)), aA);
        float gf = bp(adr_f, act);
        float gg = bp(adr_g, act);
        float go = bp(adr_o, act);
        c1 = fmaf(gf, c1, act * gg);             // lanes 0..9: act == i-gate
        float tc = fmaf(tB, __builtin_amdgcn_rcpf(1.0f + __builtin_amdgcn_exp2f(tK * c1)), tA);
        float h1u = go * tc;
        #pragma unroll
        for (int j = 0; j < HID; ++j) h1s[j] = rl(h1u, j);

        // ---- cell 2 ----
        float d0 = b2;
        float d1 = h2s[0] * whh2v[0];
        #pragma unroll
        for (int j = 0; j < HID; ++j) {
            d0 = fmaf(h1s[j], wih2v[j], d0);
            if (j) d1 = fmaf(h2s[j], whh2v[j], d1);
        }
        float d = d0 + d1;
        float act2 = fmaf(aB, __builtin_amdgcn_rcpf(1.0f + __builtin_amdgcn_exp2f(d)), aA);
        float qf = bp(adr_f, act2);
        float qg = bp(adr_g, act2);
        float qo = bp(adr_o, act2);
        c2 = fmaf(qf, c2, act2 * qg);
        float tc2 = fmaf(tB, __builtin_amdgcn_rcpf(1.0f + __builtin_amdgcn_exp2f(tK * c2)), tA);
        float h2u = qo * tc2;
        #pragma unroll
        for (int j = 0; j < HID; ++j) h2s[j] = rl(h2u, j);

        // ---- linear head: sgpr h2 x vgpr wlin (off critical path) ----
        float y = bl;
        #pragma unroll
        for (int j = 0; j < HID; ++j) y = fmaf(h2s[j], wlinv[j], y);
        return y;
    };

    // ---- main loop: 4 steps/group, x prefetched one group ahead ----
    const float4* xrow = (const float4*)(x + (size_t)ge * TMAIN);
    float4* orow = (float4*)(out + (size_t)ge * OUTW);  // OUTW=1088, rows 16B-aligned
    float4 xv = xrow[0];
    float yprev = 0.f;
    #pragma unroll 1
    for (int t4 = 0; t4 < TMAIN / 4; ++t4) {
        float4 xn = (t4 + 1 < TMAIN / 4) ? xrow[t4 + 1] : make_float4(0.f, 0.f, 0.f, 0.f);
        float4 yv;
        yv.x = step(xv.x);
        yv.y = step(xv.y);
        yv.z = step(xv.z);
        yv.w = step(xv.w);
        if (lane == 0) orow[t4] = yv;
        yprev = yv.w;
        xv = xn;
    }

    // ---- future loop: y feeds back (uniform on all lanes) ----
    int t = 0;
    #pragma unroll 1
    for (; t + 3 < F; t += 4) {
        float4 yv;
        yv.x = step(yprev);
        yv.y = step(yv.x);
        yv.z = step(yv.y);
        yv.w = step(yv.z);
        if (lane == 0) orow[(TMAIN + t) / 4] = yv;
        yprev = yv.w;
    }
    #pragma unroll 1
    for (; t < F; ++t) {
        yprev = step(yprev);
        if (lane == 0) out[(size_t)ge * OUTW + TMAIN + t] = yprev;
    }
}

extern "C" void kernel_launch(void* const* d_in, const int* in_sizes, int n_in,
                              void* d_out, int out_size, void* d_ws, size_t ws_size,
                              hipStream_t stream) {
    const float* x    = (const float*)d_in[0];
    const float* Wih1 = (const float*)d_in[1];
    const float* Whh1 = (const float*)d_in[2];
    const float* bih1 = (const float*)d_in[3];
    const float* bhh1 = (const float*)d_in[4];
    const float* Wih2 = (const float*)d_in[5];
    const float* Whh2 = (const float*)d_in[6];
    const float* bih2 = (const float*)d_in[7];
    const float* bhh2 = (const float*)d_in[8];
    const float* Wlin = (const float*)d_in[9];
    const float* blin = (const float*)d_in[10];
    const int*   futp = (const int*)d_in[11];
    float* out = (float*)d_out;

    lstm2_kernel<<<NB, 64, 0, stream>>>(x, Wih1, Whh1, bih1, bhh1,
                                        Wih2, Whh2, bih2, bhh2,
                                        Wlin, blin, futp, out);
}

// Round 6
// 454.397 us; speedup vs baseline: 1.1542x; 1.1222x over previous
//
#include <hip/hip_runtime.h>

// 2-layer LSTM (HID=10), B=2048, T=1024 main + F=64 future steps.
// One element per wave, 2048 single-wave blocks = 2 waves/SIMD on all 1024 SIMDs.
// Lane L = k*10+u owns gate row L; h1/h2 wave-uniform in SGPRs via v_readlane;
// weights prescaled by activation constant and pinned in VGPRs (waves_per_eu(2,2)
// gives the 256-VGPR budget; r5 confirmed VGPR=88, no AGPR shuttle).
//
// Round 6: SOFTWARE-PIPELINE THE TWO CELLS. Evidence: r3/r4/r5 all hit the same
// ~470us wall despite +-100 inst/step differences -> latency-chain-bound, not
// issue-bound. cell1(t+1) and cell2(t) both depend only on h1(t), so one
// pipelined iteration runs both chains in parallel (dots, acts, gathers,
// c-updates, tanhs co-scheduled), halving the serial chain per step.

#define NB 2048
#define TMAIN 1024
#define HID 10

#define PIN(v) asm volatile("" : "+v"(v))

__device__ __forceinline__ float rcp_(float v)  { return __builtin_amdgcn_rcpf(v); }
__device__ __forceinline__ float exp2_(float v) { return __builtin_amdgcn_exp2f(v); }

__global__ __launch_bounds__(64)
__attribute__((amdgpu_waves_per_eu(2, 2)))
void lstm2_kernel(
    const float* __restrict__ x,
    const float* __restrict__ Wih1, const float* __restrict__ Whh1,
    const float* __restrict__ bih1, const float* __restrict__ bhh1,
    const float* __restrict__ Wih2, const float* __restrict__ Whh2,
    const float* __restrict__ bih2, const float* __restrict__ bhh2,
    const float* __restrict__ Wlin, const float* __restrict__ blin,
    const int* __restrict__ futp,
    float* __restrict__ out)
{
    const int lane = threadIdx.x;
    const int ge   = blockIdx.x;
    const int F    = futp[0];
    const int OUTW = TMAIN + F;

    const int L = (lane < 40) ? lane : 0;
    const int k = L / HID;
    const int u = L - k * HID;

    const bool isg = (k == 2);
    const float aK = isg ?  2.8853900817779268f : -1.4426950408889634f;
    const float aA = isg ?  1.0f : 0.0f;
    const float aB = isg ? -2.0f : 1.0f;
    const float tK = 2.8853900817779268f;

    // ---- per-lane weights (row L), prescaled by aK ----
    float whh1v[HID], wih2v[HID], whh2v[HID], wlinv[HID];
    #pragma unroll
    for (int j = 0; j < HID; ++j) {
        whh1v[j] = Whh1[L * HID + j] * aK;
        wih2v[j] = Wih2[L * HID + j] * aK;
        whh2v[j] = Whh2[L * HID + j] * aK;
        wlinv[j] = Wlin[j];
    }
    float wih1v = Wih1[L] * aK;
    float b1 = (bih1[L] + bhh1[L]) * aK;
    float b2 = (bih2[L] + bhh2[L]) * aK;
    float bl = blin[0];

    #pragma unroll
    for (int j = 0; j < HID; ++j) { PIN(whh1v[j]); PIN(wih2v[j]); PIN(whh2v[j]); PIN(wlinv[j]); }
    PIN(wih1v); PIN(b1); PIN(b2); PIN(bl);

    const int adr_f = (1 * HID + u) * 4;
    const int adr_g = (2 * HID + u) * 4;
    const int adr_o = (3 * HID + u) * 4;

    auto bp = [](int addr, float v) -> float {
        return __int_as_float(__builtin_amdgcn_ds_bpermute(addr, __float_as_int(v)));
    };
    auto rl = [](float v, int j) -> float {
        return __int_as_float(__builtin_amdgcn_readlane(__float_as_int(v), j));
    };
    auto actfn = [&](float a) -> float {                 // sigma or tanh (prescaled input)
        return fmaf(aB, rcp_(1.0f + exp2_(a)), aA);
    };
    auto ctanh = [&](float c) -> float {                 // tanh for cell state
        return fmaf(-2.0f, rcp_(1.0f + exp2_(tK * c)), 1.0f);
    };

    // ---- state ----
    float c1 = 0.f, c2 = 0.f;
    float h1s[HID], h2s[HID];
    #pragma unroll
    for (int j = 0; j < HID; ++j) { h1s[j] = 0.f; h2s[j] = 0.f; }

    // Pipelined iteration t: cell2(t) [uses h1(t), h2(t-1)] AND cell1(t+1)
    // [uses h1(t), x[t+1]] run as two independent chains. Returns y(t).
    auto pipe_iter = [&](float xnext) -> float {
        // cell2(t) pre-act: 4 short chains
        float dA = fmaf(h1s[0], wih2v[0], b2);
        float dB = h1s[5] * wih2v[5];
        float dC = h2s[0] * whh2v[0];
        float dD = h2s[5] * whh2v[5];
        #pragma unroll
        for (int j = 1; j < 5; ++j) {
            dA = fmaf(h1s[j],     wih2v[j],     dA);
            dB = fmaf(h1s[5 + j], wih2v[5 + j], dB);
            dC = fmaf(h2s[j],     whh2v[j],     dC);
            dD = fmaf(h2s[5 + j], whh2v[5 + j], dD);
        }
        float d = (dA + dB) + (dC + dD);
        // cell1(t+1) pre-act: 2 chains
        float aAc = fmaf(xnext, wih1v, b1);
        float aBc = h1s[5] * whh1v[5];
        #pragma unroll
        for (int j = 0; j < 5; ++j) {
            aAc = fmaf(h1s[j], whh1v[j], aAc);
            if (j) aBc = fmaf(h1s[5 + j], whh1v[5 + j], aBc);
        }
        float a = aAc + aBc;
        // activations (interleaved trans)
        float act2 = actfn(d);
        float act1 = actfn(a);
        // gathers: 6 independent bperms, one latency stage
        float f2 = bp(adr_f, act2), g2 = bp(adr_g, act2), o2 = bp(adr_o, act2);
        float f1 = bp(adr_f, act1), g1 = bp(adr_g, act1), o1 = bp(adr_o, act1);
        // c updates (lanes 0..9 carry real state; act == i-gate there)
        c2 = fmaf(f2, c2, act2 * g2);
        c1 = fmaf(f1, c1, act1 * g1);
        float h2u = o2 * ctanh(c2);
        float h1u = o1 * ctanh(c1);
        // broadcasts
        #pragma unroll
        for (int j = 0; j < HID; ++j) { h1s[j] = rl(h1u, j); h2s[j] = rl(h2u, j); }
        // head
        float y = bl;
        #pragma unroll
        for (int j = 0; j < HID; ++j) y = fmaf(h2s[j], wlinv[j], y);
        return y;
    };

    // cell2-only step (t = TMAIN-1 tail of the pipeline). Returns y(t).
    auto cell2_only = [&]() -> float {
        float dA = fmaf(h1s[0], wih2v[0], b2);
        float dB = h1s[5] * wih2v[5];
        float dC = h2s[0] * whh2v[0];
        float dD = h2s[5] * whh2v[5];
        #pragma unroll
        for (int j = 1; j < 5; ++j) {
            dA = fmaf(h1s[j],     wih2v[j],     dA);
            dB = fmaf(h1s[5 + j], wih2v[5 + j], dB);
            dC = fmaf(h2s[j],     whh2v[j],     dC);
            dD = fmaf(h2s[5 + j], whh2v[5 + j], dD);
        }
        float act2 = actfn((dA + dB) + (dC + dD));
        float f2 = bp(adr_f, act2), g2 = bp(adr_g, act2), o2 = bp(adr_o, act2);
        c2 = fmaf(f2, c2, act2 * g2);
        float h2u = o2 * ctanh(c2);
        #pragma unroll
        for (int j = 0; j < HID; ++j) h2s[j] = rl(h2u, j);
        float y = bl;
        #pragma unroll
        for (int j = 0; j < HID; ++j) y = fmaf(h2s[j], wlinv[j], y);
        return y;
    };

    // full serial step (future loop): cell1(xt) then cell2. Returns y.
    auto fstep = [&](float xt) -> float {
        float aAc = fmaf(xt, wih1v, b1);
        float aBc = h1s[5] * whh1v[5];
        #pragma unroll
        for (int j = 0; j < 5; ++j) {
            aAc = fmaf(h1s[j], whh1v[j], aAc);
            if (j) aBc = fmaf(h1s[5 + j], whh1v[5 + j], aBc);
        }
        float act1 = actfn(aAc + aBc);
        float f1 = bp(adr_f, act1), g1 = bp(adr_g, act1), o1 = bp(adr_o, act1);
        c1 = fmaf(f1, c1, act1 * g1);
        float h1u = o1 * ctanh(c1);
        #pragma unroll
        for (int j = 0; j < HID; ++j) h1s[j] = rl(h1u, j);
        return cell2_only();
    };

    // ---- prologue: h1(0), c1(0) from x[0] (h1s == 0) ----
    const float4* xrow = (const float4*)(x + (size_t)ge * TMAIN);
    float4* orow = (float4*)(out + (size_t)ge * OUTW);   // OUTW=1088, 16B-aligned rows
    float4 xv = xrow[0];
    {
        float act1 = actfn(fmaf(xv.x, wih1v, b1));
        float g1 = bp(adr_g, act1), o1 = bp(adr_o, act1);
        c1 = act1 * g1;                                   // f-term: c1_old == 0
        float h1u = o1 * ctanh(c1);
        #pragma unroll
        for (int j = 0; j < HID; ++j) h1s[j] = rl(h1u, j);
    }

    // ---- main loop: 255 groups of 4 pipelined iterations ----
    #pragma unroll 1
    for (int t4 = 0; t4 < TMAIN / 4 - 1; ++t4) {
        float4 xn = xrow[t4 + 1];
        float y0 = pipe_iter(xv.y);
        float y1 = pipe_iter(xv.z);
        float y2 = pipe_iter(xv.w);
        float y3 = pipe_iter(xn.x);
        if (lane == 0) orow[t4] = make_float4(y0, y1, y2, y3);
        xv = xn;
    }
    // epilogue: t = 1020..1022 pipelined, t = 1023 cell2-only
    {
        float y0 = pipe_iter(xv.y);
        float y1 = pipe_iter(xv.z);
        float y2 = pipe_iter(xv.w);
        float y3 = cell2_only();
        if (lane == 0) orow[TMAIN / 4 - 1] = make_float4(y0, y1, y2, y3);
    }

    // ---- future loop: serial (y feeds back) ----
    float yprev = 0.f;
    {
        // recover y(1023) on all lanes: it's uniform (computed in cell2_only)
        // recompute head from h2s (cheap) to avoid threading it out of the block above
        float y = bl;
        #pragma unroll
        for (int j = 0; j < HID; ++j) y = fmaf(h2s[j], wlinv[j], y);
        yprev = y;
    }
    int t = 0;
    #pragma unroll 1
    for (; t + 3 < F; t += 4) {
        float y0 = fstep(yprev);
        float y1 = fstep(y0);
        float y2 = fstep(y1);
        float y3 = fstep(y2);
        if (lane == 0) orow[(TMAIN + t) / 4] = make_float4(y0, y1, y2, y3);
        yprev = y3;
    }
    #pragma unroll 1
    for (; t < F; ++t) {
        yprev = fstep(yprev);
        if (lane == 0) out[(size_t)ge * OUTW + TMAIN + t] = yprev;
    }
}

extern "C" void kernel_launch(void* const* d_in, const int* in_sizes, int n_in,
                              void* d_out, int out_size, void* d_ws, size_t ws_size,
                              hipStream_t stream) {
    const float* x    = (const float*)d_in[0];
    const float* Wih1 = (const float*)d_in[1];
    const float* Whh1 = (const float*)d_in[2];
    const float* bih1 = (const float*)d_in[3];
    const float* bhh1 = (const float*)d_in[4];
    const float* Wih2 = (const float*)d_in[5];
    const float* Whh2 = (const float*)d_in[6];
    const float* bih2 = (const float*)d_in[7];
    const float* bhh2 = (const float*)d_in[8];
    const float* Wlin = (const float*)d_in[9];
    const float* blin = (const float*)d_in[10];
    const int*   futp = (const int*)d_in[11];
    float* out = (float*)d_out;

    lstm2_kernel<<<NB, 64, 0, stream>>>(x, Wih1, Whh1, bih1, bhh1,
                                        Wih2, Whh2, bih2, bhh2,
                                        Wlin, blin, futp, out);
}

// Round 7
// 444.223 us; speedup vs baseline: 1.1806x; 1.0229x over previous
//
#include <hip/hip_runtime.h>

// 2-layer LSTM (HID=10), B=2048, T=1024 main + F=64 future steps.
// One element per wave, 2048 single-wave blocks = 2 waves/SIMD on all 1024 SIMDs.
// Lane L = k*10+u owns gate row L; cells software-pipelined (cell1(t+1) || cell2(t)).
//
// Round 7: VALU-pipe diet. r6 counters: wall 915 cyc/SIMD/step, VALUBusy 72%
// -> VALU-issue-bound (660 cyc/SIMD/step busy), trans/DS pipes underused.
//  a) dots+head in PACKED fp32 (v_pk_fma_f32 via ext_vector_type(2) +
//     __builtin_elementwise_fma): ~41 -> ~21 dot ops, dep chains halved.
//  b) h broadcast via ds_bpermute (DS pipe) instead of v_readlane (VALU pipe).
//  c) tK folded into g-gate act constants (cell states stored pre-scaled).

#define NB 2048
#define TMAIN 1024
#define HID 10

typedef float v2f __attribute__((ext_vector_type(2)));

#define PIN2(v) asm volatile("" : "+v"(v))
#define PIN(v)  asm volatile("" : "+v"(v))

__device__ __forceinline__ float rcp_(float v)  { return __builtin_amdgcn_rcpf(v); }
__device__ __forceinline__ float exp2_(float v) { return __builtin_amdgcn_exp2f(v); }
__device__ __forceinline__ v2f mk2(float x, float y) { v2f r; r.x = x; r.y = y; return r; }
__device__ __forceinline__ v2f pfma(v2f a, v2f b, v2f c) { return __builtin_elementwise_fma(a, b, c); }

__global__ __launch_bounds__(64)
__attribute__((amdgpu_waves_per_eu(2, 2)))
void lstm2_kernel(
    const float* __restrict__ x,
    const float* __restrict__ Wih1, const float* __restrict__ Whh1,
    const float* __restrict__ bih1, const float* __restrict__ bhh1,
    const float* __restrict__ Wih2, const float* __restrict__ Whh2,
    const float* __restrict__ bih2, const float* __restrict__ bhh2,
    const float* __restrict__ Wlin, const float* __restrict__ blin,
    const int* __restrict__ futp,
    float* __restrict__ out)
{
    const int lane = threadIdx.x;
    const int ge   = blockIdx.x;
    const int F    = futp[0];
    const int OUTW = TMAIN + F;

    const int L = (lane < 40) ? lane : 0;
    const int k = L / HID;
    const int u = L - k * HID;

    const bool isg = (k == 2);
    const float aK = isg ?  2.8853900817779268f : -1.4426950408889634f;
    const float tK = 2.8853900817779268f;
    // g-gate act pre-scaled by tK: cell states carry tK*c, so ctanh needs no mul
    const float aA = isg ?  tK         : 0.0f;
    const float aB = isg ? -2.0f * tK  : 1.0f;

    // ---- per-lane weights (row L), prescaled by aK, packed in v2f pairs ----
    v2f whh1p[5], wih2p[5], whh2p[5], wlinp[5];
    #pragma unroll
    for (int j = 0; j < 5; ++j) {
        whh1p[j] = mk2(Whh1[L * HID + 2*j] * aK, Whh1[L * HID + 2*j + 1] * aK);
        wih2p[j] = mk2(Wih2[L * HID + 2*j] * aK, Wih2[L * HID + 2*j + 1] * aK);
        whh2p[j] = mk2(Whh2[L * HID + 2*j] * aK, Whh2[L * HID + 2*j + 1] * aK);
        wlinp[j] = mk2(Wlin[2*j], Wlin[2*j + 1]);
    }
    float wih1v = Wih1[L] * aK;
    float b1 = (bih1[L] + bhh1[L]) * aK;
    float b2 = (bih2[L] + bhh2[L]) * aK;
    float bl = blin[0];

    #pragma unroll
    for (int j = 0; j < 5; ++j) { PIN2(whh1p[j]); PIN2(wih2p[j]); PIN2(whh2p[j]); PIN2(wlinp[j]); }
    PIN(wih1v); PIN(b1); PIN(b2); PIN(bl);

    const int adr_f = (1 * HID + u) * 4;
    const int adr_g = (2 * HID + u) * 4;
    const int adr_o = (3 * HID + u) * 4;

    auto bp = [](int addr, float v) -> float {
        return __int_as_float(__builtin_amdgcn_ds_bpermute(addr, __float_as_int(v)));
    };
    auto actf = [&](float p) -> float {          // sigma (or tK*tanh on g-lanes)
        return fmaf(aB, rcp_(1.0f + exp2_(p)), aA);
    };
    auto ctanh = [&](float cs) -> float {        // tanh of (pre-scaled) cell state
        return fmaf(-2.0f, rcp_(1.0f + exp2_(cs)), 1.0f);
    };

    // ---- state: cs on lanes 0..9 (scaled by tK); h broadcast in v2f pairs ----
    float c1 = 0.f, c2 = 0.f;
    v2f h1p[5], h2p[5];
    #pragma unroll
    for (int j = 0; j < 5; ++j) { h1p[j] = mk2(0.f, 0.f); h2p[j] = mk2(0.f, 0.f); }

    // broadcast h (valid on lanes 0..9) into all lanes' packed arrays: DS pipe
    auto bcast1 = [&](float h1u) {
        #pragma unroll
        for (int j = 0; j < 5; ++j) { h1p[j].x = bp(8*j, h1u); h1p[j].y = bp(8*j + 4, h1u); }
    };
    auto bcast2 = [&](float h2u) {
        #pragma unroll
        for (int j = 0; j < 5; ++j) { h2p[j].x = bp(8*j, h2u); h2p[j].y = bp(8*j + 4, h2u); }
    };
    auto head = [&]() -> float {
        v2f Y = pfma(h2p[0], wlinp[0], mk2(bl, 0.f));
        #pragma unroll
        for (int j = 1; j < 5; ++j) Y = pfma(h2p[j], wlinp[j], Y);
        return Y.x + Y.y;
    };

    // Pipelined iteration t: cell2(t) and cell1(t+1) as parallel chains.
    auto pipe_iter = [&](float xnext) -> float {
        v2f U = pfma(h1p[0], wih2p[0], mk2(b2, 0.f));
        v2f V = h2p[0] * whh2p[0];
        v2f A = pfma(h1p[0], whh1p[0], mk2(fmaf(xnext, wih1v, b1), 0.f));
        #pragma unroll
        for (int j = 1; j < 5; ++j) {
            U = pfma(h1p[j], wih2p[j], U);
            V = pfma(h2p[j], whh2p[j], V);
            A = pfma(h1p[j], whh1p[j], A);
        }
        float d = (U.x + U.y) + (V.x + V.y);
        float a = A.x + A.y;
        float act2 = actf(d);
        float act1 = actf(a);
        float f2 = bp(adr_f, act2), g2 = bp(adr_g, act2), o2 = bp(adr_o, act2);
        float f1 = bp(adr_f, act1), g1 = bp(adr_g, act1), o1 = bp(adr_o, act1);
        c2 = fmaf(f2, c2, act2 * g2);            // lanes 0..9: act == i-gate
        c1 = fmaf(f1, c1, act1 * g1);
        float h2u = o2 * ctanh(c2);
        float h1u = o1 * ctanh(c1);
        bcast1(h1u); bcast2(h2u);
        return head();
    };

    auto cell2_only = [&]() -> float {
        v2f U = pfma(h1p[0], wih2p[0], mk2(b2, 0.f));
        v2f V = h2p[0] * whh2p[0];
        #pragma unroll
        for (int j = 1; j < 5; ++j) {
            U = pfma(h1p[j], wih2p[j], U);
            V = pfma(h2p[j], whh2p[j], V);
        }
        float act2 = actf((U.x + U.y) + (V.x + V.y));
        float f2 = bp(adr_f, act2), g2 = bp(adr_g, act2), o2 = bp(adr_o, act2);
        c2 = fmaf(f2, c2, act2 * g2);
        float h2u = o2 * ctanh(c2);
        bcast2(h2u);
        return head();
    };

    auto fstep = [&](float xt) -> float {        // serial step for future loop
        v2f A = pfma(h1p[0], whh1p[0], mk2(fmaf(xt, wih1v, b1), 0.f));
        #pragma unroll
        for (int j = 1; j < 5; ++j) A = pfma(h1p[j], whh1p[j], A);
        float act1 = actf(A.x + A.y);
        float f1 = bp(adr_f, act1), g1 = bp(adr_g, act1), o1 = bp(adr_o, act1);
        c1 = fmaf(f1, c1, act1 * g1);
        float h1u = o1 * ctanh(c1);
        bcast1(h1u);
        return cell2_only();
    };

    // ---- prologue: h1(0), c1(0) from x[0] ----
    const float4* xrow = (const float4*)(x + (size_t)ge * TMAIN);
    float4* orow = (float4*)(out + (size_t)ge * OUTW);   // OUTW=1088, 16B-aligned rows
    float4 xv = xrow[0];
    {
        float act1 = actf(fmaf(xv.x, wih1v, b1));
        float g1 = bp(adr_g, act1), o1 = bp(adr_o, act1);
        c1 = act1 * g1;                                   // c1_old == 0
        float h1u = o1 * ctanh(c1);
        bcast1(h1u);
    }

    // ---- main loop: 255 groups of 4 pipelined iterations ----
    #pragma unroll 1
    for (int t4 = 0; t4 < TMAIN / 4 - 1; ++t4) {
        float4 xn = xrow[t4 + 1];
        float y0 = pipe_iter(xv.y);
        float y1 = pipe_iter(xv.z);
        float y2 = pipe_iter(xv.w);
        float y3 = pipe_iter(xn.x);
        if (lane == 0) orow[t4] = make_float4(y0, y1, y2, y3);
        xv = xn;
    }
    {
        float y0 = pipe_iter(xv.y);
        float y1 = pipe_iter(xv.z);
        float y2 = pipe_iter(xv.w);
        float y3 = cell2_only();
        if (lane == 0) orow[TMAIN / 4 - 1] = make_float4(y0, y1, y2, y3);
    }

    // ---- future loop: serial (y feeds back; y is uniform on all lanes) ----
    float yprev = head();
    int t = 0;
    #pragma unroll 1
    for (; t + 3 < F; t += 4) {
        float y0 = fstep(yprev);
        float y1 = fstep(y0);
        float y2 = fstep(y1);
        float y3 = fstep(y2);
        if (lane == 0) orow[(TMAIN + t) / 4] = make_float4(y0, y1, y2, y3);
        yprev = y3;
    }
    #pragma unroll 1
    for (; t < F; ++t) {
        yprev = fstep(yprev);
        if (lane == 0) out[(size_t)ge * OUTW + TMAIN + t] = yprev;
    }
}

extern "C" void kernel_launch(void* const* d_in, const int* in_sizes, int n_in,
                              void* d_out, int out_size, void* d_ws, size_t ws_size,
                              hipStream_t stream) {
    const float* x    = (const float*)d_in[0];
    const float* Wih1 = (const float*)d_in[1];
    const float* Whh1 = (const float*)d_in[2];
    const float* bih1 = (const float*)d_in[3];
    const float* bhh1 = (const float*)d_in[4];
    const float* Wih2 = (const float*)d_in[5];
    const float* Whh2 = (const float*)d_in[6];
    const float* bih2 = (const float*)d_in[7];
    const float* bhh2 = (const float*)d_in[8];
    const float* Wlin = (const float*)d_in[9];
    const float* blin = (const float*)d_in[10];
    const int*   futp = (const int*)d_in[11];
    float* out = (float*)d_out;

    lstm2_kernel<<<NB, 64, 0, stream>>>(x, Wih1, Whh1, bih1, bhh1,
                                        Wih2, Whh2, bih2, bhh2,
                                        Wlin, blin, futp, out);
}